// Round 5
// baseline (404.927 us; speedup 1.0000x reference)
//
#include <hip/hip_runtime.h>

#define RES   128
#define FEAT  1024   // map_num(128) * feat_dim(8)
#define NBINS (RES * RES)

typedef float nfloat4 __attribute__((ext_vector_type(4)));   // native vec for NT store

// ---------------------------------------------------------------------------
// Hand-rolled grid barrier (all blocks co-resident: grid=256 <= 256 CUs,
// 1 KB LDS, low VGPR). ctr pre-zeroed by the memset dispatch each iteration;
// monotone targets let one counter serve all barriers in the launch.
// Release (wbl2) on arrival makes prior plain stores visible at the coherent
// point; acquire on the spin load + threadfence invalidates stale caches.
__device__ inline void grid_barrier(unsigned* ctr, unsigned target)
{
    __syncthreads();                       // also drains each wave's vmem (compiler waitcnt)
    if (threadIdx.x == 0) {
        __threadfence();                   // release: flush this XCD's dirty L2 lines
        __hip_atomic_fetch_add(ctr, 1u, __ATOMIC_ACQ_REL, __HIP_MEMORY_SCOPE_AGENT);
        while (__hip_atomic_load(ctr, __ATOMIC_ACQUIRE, __HIP_MEMORY_SCOPE_AGENT) < target) {
            __builtin_amdgcn_s_sleep(2);
        }
        __threadfence();                   // acquire: invalidate L1/L2 for cross-XCD reads
    }
    __syncthreads();
}

// ---------------------------------------------------------------------------
// Fused sort: histogram -> distributed exclusive scan -> scatter of packed
// records, one plain launch (grid barriers via ws counter). Requires
// N == 65536 (grid = 256 blocks x 256 thr). hist must be pre-zeroed.
// Output: sorted[pos] = {u, v, bitcast(pid), 0}; hist[c] = inclusive end.
__global__ __launch_bounds__(256)
void sort_fused_kernel(const float* __restrict__ inputs,
                       unsigned* __restrict__ hist,
                       unsigned* __restrict__ bsum,    // [64]
                       unsigned* __restrict__ ctr,     // [1], pre-zeroed
                       float4* __restrict__ sorted,
                       int N)
{
    __shared__ unsigned sc[256];
    const int t   = threadIdx.x;
    const int tid = blockIdx.x * 256 + t;

    // phase 1: histogram (keep uv + cell in registers for the scatter)
    float2 uv = make_float2(0.f, 0.f);
    int cell = 0;
    if (tid < N) {
        uv = ((const float2*)inputs)[tid];
        const int i0 = (int)floorf(uv.x * (float)(RES - 1));
        const int i1 = (int)floorf(uv.y * (float)(RES - 1));
        cell = i0 * RES + i1;
        atomicAdd(&hist[cell], 1u);
    }
    grid_barrier(ctr, 256u);

    // phase 2a: per-block scan — block b (b<64) scans bins [b*256, b*256+256)
    if (blockIdx.x < 64) {
        const int idx = blockIdx.x * 256 + t;
        // atomic agent load: bypass private L2 (atomics live at coherent point)
        const unsigned v = __hip_atomic_load(&hist[idx], __ATOMIC_RELAXED,
                                             __HIP_MEMORY_SCOPE_AGENT);
        sc[t] = v;
        __syncthreads();
        for (int off = 1; off < 256; off <<= 1) {
            const unsigned u = (t >= off) ? sc[t - off] : 0u;
            __syncthreads();
            sc[t] += u;
            __syncthreads();
        }
        const unsigned incl = sc[t];
        hist[idx] = incl - v;              // block-local exclusive (single-writer lines)
        if (t == 255)
            __hip_atomic_store(&bsum[blockIdx.x], incl, __ATOMIC_RELAXED,
                               __HIP_MEMORY_SCOPE_AGENT);   // avoid false sharing
    }
    grid_barrier(ctr, 512u);

    // phase 2b: exclusive scan of the 64 block sums (block 0, wave 0)
    if (blockIdx.x == 0 && t < 64) {
        unsigned v = __hip_atomic_load(&bsum[t], __ATOMIC_RELAXED,
                                       __HIP_MEMORY_SCOPE_AGENT);
        const unsigned orig = v;
        for (int off = 1; off < 64; off <<= 1) {
            const unsigned u = __shfl_up(v, off, 64);
            if (t >= off) v += u;
        }
        __hip_atomic_store(&bsum[t], v - orig, __ATOMIC_RELAXED,
                           __HIP_MEMORY_SCOPE_AGENT);
    }
    grid_barrier(ctr, 768u);

    // phase 2c: add block offsets -> hist holds global exclusive prefix
    if (blockIdx.x < 64) {
        const int idx = blockIdx.x * 256 + t;
        const unsigned add = __hip_atomic_load(&bsum[blockIdx.x], __ATOMIC_RELAXED,
                                               __HIP_MEMORY_SCOPE_AGENT);
        hist[idx] += add;                  // own line, flushed by next release
    }
    grid_barrier(ctr, 1024u);

    // phase 3: scatter packed records; hist[c] becomes inclusive end
    if (tid < N) {
        const unsigned pos = atomicAdd(&hist[cell], 1u);
        float4 e;
        e.x = uv.x;
        e.y = uv.y;
        e.z = __uint_as_float((unsigned)tid);
        e.w = 0.0f;
        sorted[pos] = e;
    }
}

// ---------------------------------------------------------------------------
// Main pass: one block per CELL. 4 neighbor rows in registers (loaded once);
// the cell's packed records are staged to LDS in ONE coalesced parallel load
// per 256-chunk, then the point loop is LDS-broadcast -> pure VALU -> one NT
// wave-store. XCD swizzle: block b -> XCD (b%8) owns a contiguous cell range.
__global__ __launch_bounds__(256)
void DenseMap_cell_kernel(const float* __restrict__ emb,
                          const unsigned* __restrict__ hist,   // inclusive ends
                          const float4* __restrict__ sorted,
                          float* __restrict__ out,
                          int chunk)
{
    const int b    = blockIdx.x;
    const int cell = (b & 7) * chunk + (b >> 3);
    const int c    = threadIdx.x;

    const unsigned start = (cell == 0) ? 0u : hist[cell - 1];
    const unsigned end   = hist[cell];
    if (start == end) return;             // boundary cells (i0==127 || i1==127)
                                          // are always empty -> no OOB rows below

    const int i0 = cell >> 7;             // cell = i0*RES + i1
    const int i1 = cell & (RES - 1);

    const long base = (long)cell * FEAT;
    const float4 r00 = ((const float4*)(emb + base))[c];
    const float4 r01 = ((const float4*)(emb + base + FEAT))[c];
    const float4 r10 = ((const float4*)(emb + base + (long)RES * FEAT))[c];
    const float4 r11 = ((const float4*)(emb + base + (long)RES * FEAT + FEAT))[c];

    __shared__ float4 se[256];

    for (unsigned cb = start; cb < end; cb += 256u) {
        const int cnt = (int)min(end - cb, 256u);
        if (c < cnt) se[c] = sorted[cb + c];
        __syncthreads();

        for (int j = 0; j < cnt; ++j) {
            const float4 e = se[j];                  // LDS broadcast
            const unsigned p = __float_as_uint(e.z);

            const float x0  = e.x * (float)(RES - 1);
            const float x1  = e.y * (float)(RES - 1);
            const float xf0 = x0 - (float)i0;        // == frac(x0) for this cell
            const float xf1 = x1 - (float)i1;

            const float w00 = (1.0f - xf0) * (1.0f - xf1);
            const float w01 = (1.0f - xf0) * xf1;
            const float w10 = xf0 * (1.0f - xf1);
            const float w11 = xf0 * xf1;

            nfloat4 r;
            r.x = r00.x * w00 + r01.x * w01 + r10.x * w10 + r11.x * w11;
            r.y = r00.y * w00 + r01.y * w01 + r10.y * w10 + r11.y * w11;
            r.z = r00.z * w00 + r01.z * w01 + r10.z * w10 + r11.z * w11;
            r.w = r00.w * w00 + r01.w * w01 + r10.w * w10 + r11.w * w11;

            __builtin_nontemporal_store(r, ((nfloat4*)(out + (long)p * FEAT)) + c);
        }
        __syncthreads();
    }
}

// ---------------------------------------------------------------------------
// Fallback: used only if ws too small or N != 65536.
__global__ __launch_bounds__(256)
void DenseMap_fallback_kernel(const float* __restrict__ inputs,
                              const float* __restrict__ emb,
                              float* __restrict__ out)
{
    const int p = blockIdx.x;
    const int c = threadIdx.x;

    const float x0 = inputs[2 * p + 0] * (float)(RES - 1);
    const float x1 = inputs[2 * p + 1] * (float)(RES - 1);
    const float f0 = floorf(x0);
    const float f1 = floorf(x1);
    const int   i0 = (int)f0;
    const int   i1 = (int)f1;
    const float xf0 = x0 - f0;
    const float xf1 = x1 - f1;

    const float w00 = (1.0f - xf0) * (1.0f - xf1);
    const float w01 = (1.0f - xf0) * xf1;
    const float w10 = xf0 * (1.0f - xf1);
    const float w11 = xf0 * xf1;

    const long base = (long)(i0 * RES + i1) * FEAT;
    const float4 a = ((const float4*)(emb + base))[c];
    const float4 b = ((const float4*)(emb + base + FEAT))[c];
    const float4 g = ((const float4*)(emb + base + (long)RES * FEAT))[c];
    const float4 h = ((const float4*)(emb + base + (long)RES * FEAT + FEAT))[c];

    float4 r;
    r.x = a.x * w00 + b.x * w01 + g.x * w10 + h.x * w11;
    r.y = a.y * w00 + b.y * w01 + g.y * w10 + h.y * w11;
    r.z = a.z * w00 + b.z * w01 + g.z * w10 + h.z * w11;
    r.w = a.w * w00 + b.w * w01 + g.w * w10 + h.w * w11;

    ((float4*)(out + (long)p * FEAT))[c] = r;
}

extern "C" void kernel_launch(void* const* d_in, const int* in_sizes, int n_in,
                              void* d_out, int out_size, void* d_ws, size_t ws_size,
                              hipStream_t stream)
{
    const float* inputs = (const float*)d_in[0];   // (batch, 2) fp32
    const float* emb    = (const float*)d_in[1];   // (16384, 1024) fp32
    float*       out    = (float*)d_out;           // (batch, 1024) fp32

    const int N = in_sizes[0] / 2;                 // 65536
    const size_t aux  = (size_t)NBINS * sizeof(unsigned) + 256 * sizeof(unsigned);
    const size_t need = (size_t)N * sizeof(float4) + aux;

    if (N == 65536 && ws_size >= need) {
        float4*   sorted = (float4*)d_ws;            // [N] packed {u, v, pid, 0}
        unsigned* hist   = (unsigned*)(sorted + N);  // [NBINS]
        unsigned* bsum   = hist + NBINS;             // [64]
        unsigned* ctr    = bsum + 64;                // [1] barrier counter

        (void)hipMemsetAsync(hist, 0, aux, stream);  // hist + bsum + ctr
        sort_fused_kernel<<<256, 256, 0, stream>>>(inputs, hist, bsum, ctr, sorted, N);
        DenseMap_cell_kernel<<<NBINS, 256, 0, stream>>>(emb, hist, sorted, out, NBINS / 8);
    } else {
        DenseMap_fallback_kernel<<<N, 256, 0, stream>>>(inputs, emb, out);
    }
}

// Round 6
// 350.272 us; speedup vs baseline: 1.1560x; 1.1560x over previous
//
#include <hip/hip_runtime.h>

#define RES   128
#define FEAT  1024   // map_num(128) * feat_dim(8)
#define NBINS (RES * RES)

typedef float nfloat4 __attribute__((ext_vector_type(4)));   // native vec for NT store

// ---------------------------------------------------------------------------
// Pass B: histogram points per grid cell
__global__ __launch_bounds__(256)
void hist_kernel(const float* __restrict__ inputs, unsigned* __restrict__ hist, int N)
{
    int p = blockIdx.x * 256 + threadIdx.x;
    if (p >= N) return;
    const float2 uv = ((const float2*)inputs)[p];
    int i0 = (int)floorf(uv.x * (float)(RES - 1));
    int i1 = (int)floorf(uv.y * (float)(RES - 1));
    atomicAdd(&hist[i0 * RES + i1], 1u);
}

// ---------------------------------------------------------------------------
// Pass C: in-place exclusive scan of 16384 bins (single block, 256 thr x 64)
__global__ __launch_bounds__(256)
void scan_kernel(unsigned* __restrict__ hist)
{
    __shared__ unsigned part[256];
    int t = threadIdx.x;
    int base = t * 64;
    unsigned s = 0;
    for (int k = 0; k < 64; ++k) s += hist[base + k];
    part[t] = s;
    __syncthreads();
    if (t == 0) {
        unsigned run = 0;
        for (int i = 0; i < 256; ++i) { unsigned v = part[i]; part[i] = run; run += v; }
    }
    __syncthreads();
    unsigned run = part[t];
    for (int k = 0; k < 64; ++k) { unsigned v = hist[base + k]; hist[base + k] = run; run += v; }
}

// ---------------------------------------------------------------------------
// Pass D: scatter PACKED records {u, v, bitcast(pid), 0} into cell-sorted
// order. After this pass hist[c] == inclusive end offset of cell c.
__global__ __launch_bounds__(256)
void scatter_kernel(const float* __restrict__ inputs, unsigned* __restrict__ hist,
                    float4* __restrict__ sorted, int N)
{
    int p = blockIdx.x * 256 + threadIdx.x;
    if (p >= N) return;
    const float2 uv = ((const float2*)inputs)[p];
    int i0 = (int)floorf(uv.x * (float)(RES - 1));
    int i1 = (int)floorf(uv.y * (float)(RES - 1));
    unsigned pos = atomicAdd(&hist[i0 * RES + i1], 1u);
    float4 e;
    e.x = uv.x;
    e.y = uv.y;
    e.z = __uint_as_float((unsigned)p);
    e.w = 0.0f;
    sorted[pos] = e;
}

// ---------------------------------------------------------------------------
// Main pass: one block per CELL. Boundary cells rejected geometrically so the
// 4 row loads issue BEFORE the hist-dependent branch (removes a ~200-cycle
// scalar-load serialization from the block critical path). The cell's packed
// records are staged to LDS in one coalesced 16 B/lane load per 256-chunk,
// then the point loop is LDS-broadcast -> pure VALU -> one NT wave-store.
// XCD swizzle: block b -> XCD (b%8) owns a contiguous cell range.
__global__ __launch_bounds__(256)
void DenseMap_cell_kernel(const float* __restrict__ emb,
                          const unsigned* __restrict__ hist,   // inclusive ends
                          const float4* __restrict__ sorted,
                          float* __restrict__ out,
                          int chunk)
{
    const int b    = blockIdx.x;
    const int cell = (b & 7) * chunk + (b >> 3);
    const int c    = threadIdx.x;

    const int i0 = cell >> 7;             // cell = i0*RES + i1
    const int i1 = cell & (RES - 1);
    if (i0 == RES - 1 || i1 == RES - 1) return;   // boundary: always empty,
                                                  // and rows would run OOB

    // Row loads depend only on blockIdx -> issue before the hist loads.
    const long base = (long)cell * FEAT;
    const float4 r00 = ((const float4*)(emb + base))[c];
    const float4 r01 = ((const float4*)(emb + base + FEAT))[c];
    const float4 r10 = ((const float4*)(emb + base + (long)RES * FEAT))[c];
    const float4 r11 = ((const float4*)(emb + base + (long)RES * FEAT + FEAT))[c];

    const unsigned start = (cell == 0) ? 0u : hist[cell - 1];
    const unsigned end   = hist[cell];
    if (start == end) return;             // ~1.7% of interior cells: rows wasted

    __shared__ float4 se[256];

    for (unsigned cb = start; cb < end; cb += 256u) {
        const int cnt = (int)min(end - cb, 256u);
        if (c < cnt) se[c] = sorted[cb + c];
        __syncthreads();

        for (int j = 0; j < cnt; ++j) {
            const float4 e = se[j];                  // LDS broadcast
            const unsigned p = __float_as_uint(e.z);

            const float x0  = e.x * (float)(RES - 1);
            const float x1  = e.y * (float)(RES - 1);
            const float xf0 = x0 - (float)i0;        // == frac(x0) for this cell
            const float xf1 = x1 - (float)i1;

            const float w00 = (1.0f - xf0) * (1.0f - xf1);
            const float w01 = (1.0f - xf0) * xf1;
            const float w10 = xf0 * (1.0f - xf1);
            const float w11 = xf0 * xf1;

            nfloat4 r;
            r.x = r00.x * w00 + r01.x * w01 + r10.x * w10 + r11.x * w11;
            r.y = r00.y * w00 + r01.y * w01 + r10.y * w10 + r11.y * w11;
            r.z = r00.z * w00 + r01.z * w01 + r10.z * w10 + r11.z * w11;
            r.w = r00.w * w00 + r01.w * w01 + r10.w * w10 + r11.w * w11;

            __builtin_nontemporal_store(r, ((nfloat4*)(out + (long)p * FEAT)) + c);
        }
        __syncthreads();
    }
}

// ---------------------------------------------------------------------------
// Fallback: used only if ws is too small for the sort buffers.
__global__ __launch_bounds__(256)
void DenseMap_fallback_kernel(const float* __restrict__ inputs,
                              const float* __restrict__ emb,
                              float* __restrict__ out)
{
    const int p = blockIdx.x;
    const int c = threadIdx.x;

    const float x0 = inputs[2 * p + 0] * (float)(RES - 1);
    const float x1 = inputs[2 * p + 1] * (float)(RES - 1);
    const float f0 = floorf(x0);
    const float f1 = floorf(x1);
    const int   i0 = (int)f0;
    const int   i1 = (int)f1;
    const float xf0 = x0 - f0;
    const float xf1 = x1 - f1;

    const float w00 = (1.0f - xf0) * (1.0f - xf1);
    const float w01 = (1.0f - xf0) * xf1;
    const float w10 = xf0 * (1.0f - xf1);
    const float w11 = xf0 * xf1;

    const long base = (long)(i0 * RES + i1) * FEAT;
    const float4 a = ((const float4*)(emb + base))[c];
    const float4 b = ((const float4*)(emb + base + FEAT))[c];
    const float4 g = ((const float4*)(emb + base + (long)RES * FEAT))[c];
    const float4 h = ((const float4*)(emb + base + (long)RES * FEAT + FEAT))[c];

    float4 r;
    r.x = a.x * w00 + b.x * w01 + g.x * w10 + h.x * w11;
    r.y = a.y * w00 + b.y * w01 + g.y * w10 + h.y * w11;
    r.z = a.z * w00 + b.z * w01 + g.z * w10 + h.z * w11;
    r.w = a.w * w00 + b.w * w01 + g.w * w10 + h.w * w11;

    ((float4*)(out + (long)p * FEAT))[c] = r;
}

extern "C" void kernel_launch(void* const* d_in, const int* in_sizes, int n_in,
                              void* d_out, int out_size, void* d_ws, size_t ws_size,
                              hipStream_t stream)
{
    const float* inputs = (const float*)d_in[0];   // (batch, 2) fp32
    const float* emb    = (const float*)d_in[1];   // (16384, 1024) fp32
    float*       out    = (float*)d_out;           // (batch, 1024) fp32

    const int N = in_sizes[0] / 2;                 // 65536
    const size_t need = (size_t)N * sizeof(float4) + (size_t)NBINS * sizeof(unsigned);

    if (ws_size >= need) {
        float4*   sorted = (float4*)d_ws;          // [N] packed {u, v, pid, 0}
        unsigned* hist   = (unsigned*)(sorted + N);// [NBINS]

        (void)hipMemsetAsync(hist, 0, NBINS * sizeof(unsigned), stream);
        hist_kernel<<<(N + 255) / 256, 256, 0, stream>>>(inputs, hist, N);
        scan_kernel<<<1, 256, 0, stream>>>(hist);
        scatter_kernel<<<(N + 255) / 256, 256, 0, stream>>>(inputs, hist, sorted, N);

        DenseMap_cell_kernel<<<NBINS, 256, 0, stream>>>(emb, hist, sorted, out, NBINS / 8);
    } else {
        DenseMap_fallback_kernel<<<N, 256, 0, stream>>>(inputs, emb, out);
    }
}